// Round 1
// baseline (737.456 us; speedup 1.0000x reference)
//
#include <hip/hip_runtime.h>
#include <math.h>

constexpr int NUM_GRAPHS = 1024;
constexpr int HIDDEN     = 256;   // 64 float4 per row

// ---------------------------------------------------------------------------
// Kernel 0: detect whether `batch` was staged as int32 or int64.
// If int64 (little-endian, values in [0,1024)), every odd 32-bit word in the
// first n words is a zero high-word. If int32 (sorted, ~488 nodes/graph),
// odd words in the bulk are nonzero graph ids. Writes flag=1 for int32.
// ---------------------------------------------------------------------------
__global__ void detect_i32_kernel(const int* __restrict__ words, int n,
                                  int* __restrict__ flag) {
    __shared__ int any_nz;
    if (threadIdx.x == 0) any_nz = 0;
    __syncthreads();
    int acc = 0;
    for (int j = 1 + 2 * (int)threadIdx.x; j < n; j += 2 * (int)blockDim.x)
        acc |= words[j];
    if (acc) atomicOr(&any_nz, 1);
    __syncthreads();
    if (threadIdx.x == 0) *flag = any_nz;
}

// ---------------------------------------------------------------------------
// Kernel 1: segment starts from the sorted batch vector.
// seg[g] = first node index with batch >= g; seg[NUM_GRAPHS] = n.
// Handles empty segments (seg[g]==seg[g+1]).
// ---------------------------------------------------------------------------
__global__ void seg_start_kernel(const int* __restrict__ words, int n,
                                 const int* __restrict__ flag,
                                 int* __restrict__ seg) {
    int i = blockIdx.x * blockDim.x + threadIdx.x;
    if (i >= n) return;
    const bool is32 = (*flag != 0);
    int b    = is32 ? words[i] : words[2 * i];
    int prev = (i == 0) ? -1 : (is32 ? words[i - 1] : words[2 * (i - 1)]);
    for (int g = prev + 1; g <= b; ++g) seg[g] = i;
    if (i == n - 1)
        for (int g = b + 1; g <= NUM_GRAPHS; ++g) seg[g] = n;
}

// ---------------------------------------------------------------------------
// Kernel 2: fused mean / max / attention pooling. One block per graph,
// 4 waves per block, one node per wave per iteration. Lane l owns columns
// 4l..4l+3 (one float4); a full wave load covers the whole 1 KB row.
// ---------------------------------------------------------------------------
__global__ __launch_bounds__(256) void pool_kernel(
    const float* __restrict__ x, const float* __restrict__ att_w,
    const float* __restrict__ att_b, const int* __restrict__ seg,
    float* __restrict__ out) {
    const int g    = blockIdx.x;
    const int lane = threadIdx.x & 63;
    const int w    = threadIdx.x >> 6;

    const int s0 = seg[g];
    const int e0 = seg[g + 1];

    const float4* __restrict__ x4 = (const float4*)x;
    const float4 wv = ((const float4*)att_w)[lane];
    const float  bias = att_b[0];

    float sx = 0.f, sy = 0.f, sz = 0.f, sw = 0.f;           // segment sum
    float mx = -INFINITY, my = -INFINITY, mz = -INFINITY, mw = -INFINITY;
    float ax = 0.f, ay = 0.f, az = 0.f, aw = 0.f;           // attention sum

    int i = s0 + w;
    if (i < e0) {
        float4 v = x4[(size_t)i * 64 + lane];
        for (;;) {
            const int inext = i + 4;
            float4 vn;
            const bool has_next = (inext < e0);
            if (has_next) vn = x4[(size_t)inext * 64 + lane];  // prefetch

            // per-row dot with attention weights, reduced across the wave
            float p = v.x * wv.x + v.y * wv.y + v.z * wv.z + v.w * wv.w;
#pragma unroll
            for (int off = 32; off >= 1; off >>= 1)
                p += __shfl_xor(p, off, 64);
            const float sig = 1.0f / (1.0f + __expf(-(p + bias)));

            sx += v.x; sy += v.y; sz += v.z; sw += v.w;
            mx = fmaxf(mx, v.x); my = fmaxf(my, v.y);
            mz = fmaxf(mz, v.z); mw = fmaxf(mw, v.w);
            ax += v.x * sig; ay += v.y * sig; az += v.z * sig; aw += v.w * sig;

            if (!has_next) break;
            v = vn;
            i = inext;
        }
    }

    // combine the 4 waves through LDS
    __shared__ float4 lsum[4][64];
    __shared__ float4 lmax[4][64];
    __shared__ float4 latt[4][64];
    lsum[w][lane] = make_float4(sx, sy, sz, sw);
    lmax[w][lane] = make_float4(mx, my, mz, mw);
    latt[w][lane] = make_float4(ax, ay, az, aw);
    __syncthreads();

    if (w == 0) {
        float4 S = lsum[0][lane], M = lmax[0][lane], A = latt[0][lane];
#pragma unroll
        for (int ww = 1; ww < 4; ++ww) {
            float4 s2 = lsum[ww][lane], m2 = lmax[ww][lane], a2 = latt[ww][lane];
            S.x += s2.x; S.y += s2.y; S.z += s2.z; S.w += s2.w;
            M.x = fmaxf(M.x, m2.x); M.y = fmaxf(M.y, m2.y);
            M.z = fmaxf(M.z, m2.z); M.w = fmaxf(M.w, m2.w);
            A.x += a2.x; A.y += a2.y; A.z += a2.z; A.w += a2.w;
        }
        const int cnt = e0 - s0;
        const float inv = 1.0f / (float)(cnt > 0 ? cnt : 1);
        float4* __restrict__ o = (float4*)(out + (size_t)g * 768);
        o[lane]       = make_float4(S.x * inv, S.y * inv, S.z * inv, S.w * inv);
        o[64 + lane]  = M;
        o[128 + lane] = A;
    }
}

extern "C" void kernel_launch(void* const* d_in, const int* in_sizes, int n_in,
                              void* d_out, int out_size, void* d_ws, size_t ws_size,
                              hipStream_t stream) {
    const float* x           = (const float*)d_in[0];
    const int*   batch_words = (const int*)d_in[1];
    const float* att_w       = (const float*)d_in[2];
    const float* att_b       = (const float*)d_in[3];
    float*       out         = (float*)d_out;
    const int n = in_sizes[1];

    int* flag = (int*)d_ws;           // 1 int
    int* seg  = ((int*)d_ws) + 8;     // NUM_GRAPHS+1 ints

    detect_i32_kernel<<<1, 1024, 0, stream>>>(batch_words, n, flag);
    seg_start_kernel<<<(n + 255) / 256, 256, 0, stream>>>(batch_words, n, flag, seg);
    pool_kernel<<<NUM_GRAPHS, 256, 0, stream>>>(x, att_w, att_b, seg, out);
}

// Round 2
// 676.825 us; speedup vs baseline: 1.0896x; 1.0896x over previous
//
#include <hip/hip_runtime.h>
#include <math.h>

constexpr int NUM_GRAPHS = 1024;

// ---------------------------------------------------------------------------
// Kernel 0: detect whether `batch` was staged as int32 or int64.
// int64 (LE, values < 1024): every odd 32-bit word is 0. int32 (sorted graph
// ids, mostly nonzero): odd words in the bulk are nonzero. flag=1 -> int32.
// flag must be zeroed before launch (hipMemsetAsync).
// ---------------------------------------------------------------------------
__global__ void detect_i32_kernel(const int* __restrict__ words, int n,
                                  int* __restrict__ flag) {
    const int stride = gridDim.x * blockDim.x;
    int acc = 0;
    for (int j = 1 + 2 * (int)(blockIdx.x * blockDim.x + threadIdx.x); j < n;
         j += 2 * stride)
        acc |= words[j];
    if (__any(acc != 0)) {
        if ((threadIdx.x & 63) == 0) atomicOr(flag, 1);
    }
}

// ---------------------------------------------------------------------------
// Kernel 1: segment starts from the sorted batch vector.
// seg[g] = first node index with batch >= g; seg[NUM_GRAPHS] = n.
// ---------------------------------------------------------------------------
__global__ void seg_start_kernel(const int* __restrict__ words, int n,
                                 const int* __restrict__ flag,
                                 int* __restrict__ seg) {
    int i = blockIdx.x * blockDim.x + threadIdx.x;
    if (i >= n) return;
    const bool is32 = (*flag != 0);
    int b    = is32 ? words[i] : words[2 * i];
    int prev = (i == 0) ? -1 : (is32 ? words[i - 1] : words[2 * (i - 1)]);
    for (int g = prev + 1; g <= b; ++g) seg[g] = i;
    if (i == n - 1)
        for (int g = b + 1; g <= NUM_GRAPHS; ++g) seg[g] = n;
}

// ---------------------------------------------------------------------------
// Kernel 2: fused mean / max / attention pooling. One block per graph, 4
// waves/block. Lane l owns columns 4l..4l+3 (one float4); a wave covers a
// full 1 KB row. Each wave processes 4 rows per iteration (rows i, i+4,
// i+8, i+12; wave stride 16) with the NEXT group's loads issued before the
// current group's compute -> up to 8 outstanding 1 KB loads per wave.
// ---------------------------------------------------------------------------
__global__ __launch_bounds__(256) void pool_kernel(
    const float* __restrict__ x, const float* __restrict__ att_w,
    const float* __restrict__ att_b, const int* __restrict__ seg,
    float* __restrict__ out) {
    const int g    = blockIdx.x;
    const int lane = threadIdx.x & 63;
    const int w    = threadIdx.x >> 6;

    const int s0 = seg[g];
    const int e0 = seg[g + 1];

    const float4* __restrict__ x4 = (const float4*)x;
    const float4 wv   = ((const float4*)att_w)[lane];
    const float  bias = att_b[0];

    float sx = 0.f, sy = 0.f, sz = 0.f, sw = 0.f;           // segment sum
    float mx = -INFINITY, my = -INFINITY, mz = -INFINITY, mw = -INFINITY;
    float ax = 0.f, ay = 0.f, az = 0.f, aw = 0.f;           // attention sum

    // process a group of 4 already-loaded rows
    auto proc4 = [&](const float4* v) {
        float p[4];
#pragma unroll
        for (int r = 0; r < 4; ++r)
            p[r] = v[r].x * wv.x + v[r].y * wv.y + v[r].z * wv.z + v[r].w * wv.w;
#pragma unroll
        for (int off = 32; off >= 1; off >>= 1) {
#pragma unroll
            for (int r = 0; r < 4; ++r)       // 4 independent chains interleave
                p[r] += __shfl_xor(p[r], off, 64);
        }
#pragma unroll
        for (int r = 0; r < 4; ++r) {
            const float sig = 1.0f / (1.0f + __expf(-(p[r] + bias)));
            sx += v[r].x; sy += v[r].y; sz += v[r].z; sw += v[r].w;
            mx = fmaxf(mx, v[r].x); my = fmaxf(my, v[r].y);
            mz = fmaxf(mz, v[r].z); mw = fmaxf(mw, v[r].w);
            ax += v[r].x * sig; ay += v[r].y * sig;
            az += v[r].z * sig; aw += v[r].w * sig;
        }
    };

    int i = s0 + w;                            // this wave's rows: i, i+4, ...
    if (i + 12 < e0) {                         // at least one full group of 4
        float4 v[4];
#pragma unroll
        for (int r = 0; r < 4; ++r)
            v[r] = x4[(size_t)(i + 4 * r) * 64 + lane];
        int nb = i + 16;
        while (nb + 12 < e0) {
            float4 vn[4];
#pragma unroll
            for (int r = 0; r < 4; ++r)        // prefetch next group
                vn[r] = x4[(size_t)(nb + 4 * r) * 64 + lane];
            proc4(v);
#pragma unroll
            for (int r = 0; r < 4; ++r) v[r] = vn[r];
            nb += 16;
        }
        proc4(v);
        i = nb;                                // first unprocessed row
    }
    for (; i < e0; i += 4) {                   // remainder (<= 3 rows/wave)
        const float4 v = x4[(size_t)i * 64 + lane];
        float p = v.x * wv.x + v.y * wv.y + v.z * wv.z + v.w * wv.w;
#pragma unroll
        for (int off = 32; off >= 1; off >>= 1)
            p += __shfl_xor(p, off, 64);
        const float sig = 1.0f / (1.0f + __expf(-(p + bias)));
        sx += v.x; sy += v.y; sz += v.z; sw += v.w;
        mx = fmaxf(mx, v.x); my = fmaxf(my, v.y);
        mz = fmaxf(mz, v.z); mw = fmaxf(mw, v.w);
        ax += v.x * sig; ay += v.y * sig; az += v.z * sig; aw += v.w * sig;
    }

    // combine the 4 waves through LDS
    __shared__ float4 lsum[4][64];
    __shared__ float4 lmax[4][64];
    __shared__ float4 latt[4][64];
    lsum[w][lane] = make_float4(sx, sy, sz, sw);
    lmax[w][lane] = make_float4(mx, my, mz, mw);
    latt[w][lane] = make_float4(ax, ay, az, aw);
    __syncthreads();

    if (w == 0) {
        float4 S = lsum[0][lane], M = lmax[0][lane], A = latt[0][lane];
#pragma unroll
        for (int ww = 1; ww < 4; ++ww) {
            float4 s2 = lsum[ww][lane], m2 = lmax[ww][lane], a2 = latt[ww][lane];
            S.x += s2.x; S.y += s2.y; S.z += s2.z; S.w += s2.w;
            M.x = fmaxf(M.x, m2.x); M.y = fmaxf(M.y, m2.y);
            M.z = fmaxf(M.z, m2.z); M.w = fmaxf(M.w, m2.w);
            A.x += a2.x; A.y += a2.y; A.z += a2.z; A.w += a2.w;
        }
        const int cnt = e0 - s0;
        const float inv = 1.0f / (float)(cnt > 0 ? cnt : 1);
        float4* __restrict__ o = (float4*)(out + (size_t)g * 768);
        o[lane]       = make_float4(S.x * inv, S.y * inv, S.z * inv, S.w * inv);
        o[64 + lane]  = M;
        o[128 + lane] = A;
    }
}

extern "C" void kernel_launch(void* const* d_in, const int* in_sizes, int n_in,
                              void* d_out, int out_size, void* d_ws, size_t ws_size,
                              hipStream_t stream) {
    const float* x           = (const float*)d_in[0];
    const int*   batch_words = (const int*)d_in[1];
    const float* att_w       = (const float*)d_in[2];
    const float* att_b       = (const float*)d_in[3];
    float*       out         = (float*)d_out;
    const int n = in_sizes[1];

    int* flag = (int*)d_ws;           // 1 int
    int* seg  = ((int*)d_ws) + 8;     // NUM_GRAPHS+1 ints

    hipMemsetAsync(flag, 0, sizeof(int), stream);
    detect_i32_kernel<<<256, 256, 0, stream>>>(batch_words, n, flag);
    seg_start_kernel<<<(n + 255) / 256, 256, 0, stream>>>(batch_words, n, flag, seg);
    pool_kernel<<<NUM_GRAPHS, 256, 0, stream>>>(x, att_w, att_b, seg, out);
}

// Round 3
// 650.875 us; speedup vs baseline: 1.1330x; 1.0399x over previous
//
#include <hip/hip_runtime.h>
#include <math.h>

constexpr int NUM_GRAPHS = 1024;
constexpr int QUARTERS   = 4;     // blocks per graph
constexpr int WAVES_PB   = 4;     // waves per block
constexpr int STRIDE     = QUARTERS * WAVES_PB;   // 16 row-stripes per graph

// ---------------------------------------------------------------------------
// Kernel 0: detect whether `batch` was staged as int32 or int64.
// int64 (LE, values < 1024): every odd 32-bit word is 0. int32 (sorted graph
// ids, mostly nonzero): odd words in the bulk are nonzero. flag=1 -> int32.
// flag must be zeroed before launch (hipMemsetAsync).
// ---------------------------------------------------------------------------
__global__ void detect_i32_kernel(const int* __restrict__ words, int n,
                                  int* __restrict__ flag) {
    const int stride = gridDim.x * blockDim.x;
    int acc = 0;
    for (int j = 1 + 2 * (int)(blockIdx.x * blockDim.x + threadIdx.x); j < n;
         j += 2 * stride)
        acc |= words[j];
    if (__any(acc != 0)) {
        if ((threadIdx.x & 63) == 0) atomicOr(flag, 1);
    }
}

// ---------------------------------------------------------------------------
// Kernel 1: segment starts from the sorted batch vector.
// seg[g] = first node index with batch >= g; seg[NUM_GRAPHS] = n.
// ---------------------------------------------------------------------------
__global__ void seg_start_kernel(const int* __restrict__ words, int n,
                                 const int* __restrict__ flag,
                                 int* __restrict__ seg) {
    int i = blockIdx.x * blockDim.x + threadIdx.x;
    if (i >= n) return;
    const bool is32 = (*flag != 0);
    int b    = is32 ? words[i] : words[2 * i];
    int prev = (i == 0) ? -1 : (is32 ? words[i - 1] : words[2 * (i - 1)]);
    for (int g = prev + 1; g <= b; ++g) seg[g] = i;
    if (i == n - 1)
        for (int g = b + 1; g <= NUM_GRAPHS; ++g) seg[g] = n;
}

// ---------------------------------------------------------------------------
// Kernel 2: fused pooling partials. 4 blocks per graph (gridDim=4096), 4
// waves per block; the 16 waves of a graph stripe its rows (stride 16).
// Lane l owns columns 4l..4l+3. Each wave processes 4 rows per iteration
// with the next group's 4 loads prefetched (up to 8 KB in flight / wave).
// Partials (sum/max/att, 3 x 256 floats) go to ws.
// ---------------------------------------------------------------------------
__global__ __launch_bounds__(256) void pool_partial_kernel(
    const float* __restrict__ x, const float* __restrict__ att_w,
    const float* __restrict__ att_b, const int* __restrict__ seg,
    float* __restrict__ part) {
    const int g    = blockIdx.x >> 2;          // graph
    const int q    = blockIdx.x & 3;           // quarter
    const int lane = threadIdx.x & 63;
    const int w    = threadIdx.x >> 6;
    const int W    = q * WAVES_PB + w;         // stripe id in [0,16)

    const int s0 = seg[g];
    const int e0 = seg[g + 1];

    const float4* __restrict__ x4 = (const float4*)x;
    const float4 wv   = ((const float4*)att_w)[lane];
    const float  bias = att_b[0];

    float sx = 0.f, sy = 0.f, sz = 0.f, sw = 0.f;
    float mx = -INFINITY, my = -INFINITY, mz = -INFINITY, mw = -INFINITY;
    float ax = 0.f, ay = 0.f, az = 0.f, aw = 0.f;

    auto proc4 = [&](const float4* v) {
        float p[4];
#pragma unroll
        for (int r = 0; r < 4; ++r)
            p[r] = v[r].x * wv.x + v[r].y * wv.y + v[r].z * wv.z + v[r].w * wv.w;
#pragma unroll
        for (int off = 32; off >= 1; off >>= 1) {
#pragma unroll
            for (int r = 0; r < 4; ++r)
                p[r] += __shfl_xor(p[r], off, 64);
        }
#pragma unroll
        for (int r = 0; r < 4; ++r) {
            const float sig = 1.0f / (1.0f + __expf(-(p[r] + bias)));
            sx += v[r].x; sy += v[r].y; sz += v[r].z; sw += v[r].w;
            mx = fmaxf(mx, v[r].x); my = fmaxf(my, v[r].y);
            mz = fmaxf(mz, v[r].z); mw = fmaxf(mw, v[r].w);
            ax += v[r].x * sig; ay += v[r].y * sig;
            az += v[r].z * sig; aw += v[r].w * sig;
        }
    };

    int i = s0 + W;                            // stripe rows: i, i+16, ...
    if (i + 3 * STRIDE < e0) {
        float4 v[4];
#pragma unroll
        for (int r = 0; r < 4; ++r)
            v[r] = x4[(size_t)(i + r * STRIDE) * 64 + lane];
        int nb = i + 4 * STRIDE;
        while (nb + 3 * STRIDE < e0) {
            float4 vn[4];
#pragma unroll
            for (int r = 0; r < 4; ++r)
                vn[r] = x4[(size_t)(nb + r * STRIDE) * 64 + lane];
            proc4(v);
#pragma unroll
            for (int r = 0; r < 4; ++r) v[r] = vn[r];
            nb += 4 * STRIDE;
        }
        proc4(v);
        i = nb;
    }
    for (; i < e0; i += STRIDE) {              // remainder (<= 3 rows/stripe)
        const float4 v = x4[(size_t)i * 64 + lane];
        float p = v.x * wv.x + v.y * wv.y + v.z * wv.z + v.w * wv.w;
#pragma unroll
        for (int off = 32; off >= 1; off >>= 1)
            p += __shfl_xor(p, off, 64);
        const float sig = 1.0f / (1.0f + __expf(-(p + bias)));
        sx += v.x; sy += v.y; sz += v.z; sw += v.w;
        mx = fmaxf(mx, v.x); my = fmaxf(my, v.y);
        mz = fmaxf(mz, v.z); mw = fmaxf(mw, v.w);
        ax += v.x * sig; ay += v.y * sig; az += v.z * sig; aw += v.w * sig;
    }

    // combine the 4 waves of this block through LDS
    __shared__ float4 lsum[4][64];
    __shared__ float4 lmax[4][64];
    __shared__ float4 latt[4][64];
    lsum[w][lane] = make_float4(sx, sy, sz, sw);
    lmax[w][lane] = make_float4(mx, my, mz, mw);
    latt[w][lane] = make_float4(ax, ay, az, aw);
    __syncthreads();

    if (w == 0) {
        float4 S = lsum[0][lane], M = lmax[0][lane], A = latt[0][lane];
#pragma unroll
        for (int ww = 1; ww < 4; ++ww) {
            float4 s2 = lsum[ww][lane], m2 = lmax[ww][lane], a2 = latt[ww][lane];
            S.x += s2.x; S.y += s2.y; S.z += s2.z; S.w += s2.w;
            M.x = fmaxf(M.x, m2.x); M.y = fmaxf(M.y, m2.y);
            M.z = fmaxf(M.z, m2.z); M.w = fmaxf(M.w, m2.w);
            A.x += a2.x; A.y += a2.y; A.z += a2.z; A.w += a2.w;
        }
        // partial layout: [block][section(3)][lane] as float4
        float4* __restrict__ o = (float4*)part + (size_t)blockIdx.x * 192;
        o[lane]       = S;
        o[64 + lane]  = M;
        o[128 + lane] = A;
    }
}

// ---------------------------------------------------------------------------
// Kernel 3: combine 4 quarter-partials per graph, divide mean, write out.
// Block g; threads 0..191: section = t/64 (0 sum,1 max,2 att), lane = t%64.
// ---------------------------------------------------------------------------
__global__ __launch_bounds__(256) void pool_combine_kernel(
    const float* __restrict__ part, const int* __restrict__ seg,
    float* __restrict__ out) {
    const int g = blockIdx.x;
    const int t = threadIdx.x;
    if (t >= 192) return;
    const int sec  = t >> 6;
    const int lane = t & 63;

    const float4* __restrict__ p4 = (const float4*)part;
    const size_t base = (size_t)g * 4 * 192 + sec * 64 + lane;

    float4 a = p4[base];
    if (sec == 1) {
#pragma unroll
        for (int q = 1; q < 4; ++q) {
            float4 b = p4[base + (size_t)q * 192];
            a.x = fmaxf(a.x, b.x); a.y = fmaxf(a.y, b.y);
            a.z = fmaxf(a.z, b.z); a.w = fmaxf(a.w, b.w);
        }
    } else {
#pragma unroll
        for (int q = 1; q < 4; ++q) {
            float4 b = p4[base + (size_t)q * 192];
            a.x += b.x; a.y += b.y; a.z += b.z; a.w += b.w;
        }
        if (sec == 0) {
            const int cnt = seg[g + 1] - seg[g];
            const float inv = 1.0f / (float)(cnt > 0 ? cnt : 1);
            a.x *= inv; a.y *= inv; a.z *= inv; a.w *= inv;
        }
    }
    ((float4*)(out + (size_t)g * 768))[sec * 64 + lane] = a;
}

extern "C" void kernel_launch(void* const* d_in, const int* in_sizes, int n_in,
                              void* d_out, int out_size, void* d_ws, size_t ws_size,
                              hipStream_t stream) {
    const float* x           = (const float*)d_in[0];
    const int*   batch_words = (const int*)d_in[1];
    const float* att_w       = (const float*)d_in[2];
    const float* att_b       = (const float*)d_in[3];
    float*       out         = (float*)d_out;
    const int n = in_sizes[1];

    int*   flag = (int*)d_ws;                       // 1 int
    int*   seg  = ((int*)d_ws) + 8;                 // NUM_GRAPHS+1 ints
    float* part = (float*)((char*)d_ws + 8192);     // 4096 blocks x 768 floats = 12 MB

    hipMemsetAsync(flag, 0, sizeof(int), stream);
    detect_i32_kernel<<<256, 256, 0, stream>>>(batch_words, n, flag);
    seg_start_kernel<<<(n + 255) / 256, 256, 0, stream>>>(batch_words, n, flag, seg);
    pool_partial_kernel<<<NUM_GRAPHS * QUARTERS, 256, 0, stream>>>(x, att_w, att_b, seg, part);
    pool_combine_kernel<<<NUM_GRAPHS, 256, 0, stream>>>(part, seg, out);
}